// Round 8
// baseline (424.469 us; speedup 1.0000x reference)
//
// RemixedBlock fused forward — MI355X gfx950, round 8.
// Changes vs r7: attention unpaired 1024-block grid (4 blocks/CU, balanced
// qb interleave); QKV epilogue writes V^T directly (k_vtrans deleted);
// ctxgate absorbs LN1 (emits A1 directly, gb1 buffer+launch deleted);
// WO split-K x2 with combine+residual+RMS fused into k_rms2c.
#include <hip/hip_runtime.h>
#include <hip/hip_bf16.h>

typedef unsigned short u16;
typedef unsigned int u32;
typedef __attribute__((ext_vector_type(8))) short bf16x8;
typedef __attribute__((ext_vector_type(4))) float f32x4;
typedef __attribute__((ext_vector_type(4))) u16 u16x4;

#define DEVFN __device__ __forceinline__

DEVFN u16 f2b(float f) {                    // f32 -> bf16 RNE
  u32 u = __builtin_bit_cast(u32, f);
  return (u16)((u + 0x7FFFu + ((u >> 16) & 1u)) >> 16);
}
DEVFN float b2f(u16 b) { return __builtin_bit_cast(float, (u32)b << 16); }
DEVFN u32 cvtpk(float lo, float hi) {       // packs 2 f32 -> 2 bf16 in one inst
  u32 r;
  asm("v_cvt_pk_bf16_f32 %0, %1, %2" : "=v"(r) : "v"(lo), "v"(hi));
  return r;
}

DEVFN void gll16(const void* g, void* l) {  // 16B global->LDS direct (dwordx4)
  __builtin_amdgcn_global_load_lds((const __attribute__((address_space(1))) void*)g,
                                   (__attribute__((address_space(3))) void*)l, 16, 0, 0);
}
#define BARRIER() __builtin_amdgcn_s_barrier()

template <int N> DEVFN void waitvm() {      // s_waitcnt vmcnt(N), compile-time N
  if constexpr (N == 0) asm volatile("s_waitcnt vmcnt(0)" ::: "memory");
  else if constexpr (N == 1) asm volatile("s_waitcnt vmcnt(1)" ::: "memory");
  else if constexpr (N == 2) asm volatile("s_waitcnt vmcnt(2)" ::: "memory");
  else if constexpr (N == 3) asm volatile("s_waitcnt vmcnt(3)" ::: "memory");
  else if constexpr (N == 4) asm volatile("s_waitcnt vmcnt(4)" ::: "memory");
  else if constexpr (N == 5) asm volatile("s_waitcnt vmcnt(5)" ::: "memory");
  else if constexpr (N == 6) asm volatile("s_waitcnt vmcnt(6)" ::: "memory");
  else asm volatile("s_waitcnt vmcnt(8)" ::: "memory");
}

// ---- problem dims ----
constexpr int Tc = 2048, Ec = 1024, Hc = 16, Cc = 64, BFc = 256, F4c = 4096;
constexpr int Mc = 2 * Tc;  // 4096 rows
constexpr float C8 = 0.18033688f;   // log2(e)/8  (folds 1/sqrt(64) and ln->log2)
constexpr float NEG2LOG2E = -2.8853901f;  // 1+tanh(y)=2/(1+exp2(y*NEG2LOG2E))

// ---- workspace layout (bytes); lifetimes strictly sequential per region ----
constexpr size_t MB = 1ull << 20;
constexpr size_t O_XN  = 0;                    // 8MB bf16: xn -> attn_out -> xn2
constexpr size_t O_HBF = 8 * MB;               // 32MB bf16 relu^2 out (spans 8-40)
constexpr size_t O_QB  = 40 * MB;              // 8MB q bf16 (rotary applied)
constexpr size_t O_WOP = 40 * MB;              // 2x16MB WO split-K partials (after QB/KB/VBF dead)
constexpr size_t O_H1  = 40 * MB;              // 4MB h1 f32 (after WOP dead)
constexpr size_t O_A2  = 45 * MB;              // 2MB bf16
constexpr size_t O_KB  = 48 * MB;              // 8MB k bf16
constexpr size_t O_H2  = 48 * MB;              // 4x4MB h2 partials (after KB/WOP dead)
constexpr size_t O_CQ  = 64 * MB;              // 1MB cq f32
constexpr size_t O_GO1 = 68 * MB + 512 * 1024; // 128KB
constexpr size_t O_GO2 = 68 * MB + 640 * 1024; // 128KB
constexpr size_t O_VT  = 72 * MB;              // 8MB V^T bf16 (B,H,D,T)
constexpr size_t O_GB2 = 73 * MB;              // 4MB (after VT dead)
constexpr size_t O_A1  = 77 * MB;              // 2MB bf16 (after VT dead)
constexpr size_t O_X2  = 80 * MB;              // 16MB f32 residual
constexpr size_t O_WQ  = 96 * MB, O_WK = 98 * MB, O_WV = 100 * MB, O_WO = 102 * MB;
constexpr size_t O_CBQ = 104 * MB;             // cb_qw bf16 (64x1024, 128KB)
constexpr size_t O_FCBW = O_CBQ + 128 * 1024;  // fc_bw bf16 CONTIGUOUS after cbq
constexpr size_t O_FCTM = 105 * MB;
constexpr size_t O_PJBW = 107 * MB;
constexpr size_t O_PJTM = 109 * MB;            // ends 109.5MB

// ---------------- merged f32->bf16 conversions (9 segments) ----------------
struct Cvt9 {
  const float* s[9];
  u16* d[9];
  int cum[10];   // in 4-element units
};
__global__ __launch_bounds__(256) void k_cvt(Cvt9 a) {
  int i = blockIdx.x * 256 + threadIdx.x;   // unit of 4 elements (grid exact)
  int seg = 0;
  #pragma unroll
  for (int s = 1; s < 9; s++) seg += (i >= a.cum[s]);
  int off = i - a.cum[seg];
  float4 v = *(const float4*)&a.s[seg][(size_t)off * 4];
  u16x4 o; o.x = f2b(v.x); o.y = f2b(v.y); o.z = f2b(v.z); o.w = f2b(v.w);
  *(u16x4*)&a.d[seg][(size_t)off * 4] = o;
}

// ---------------- block reduction helper (256 threads) ----------------
DEVFN float bsum256(float v, float* sb) {
  #pragma unroll
  for (int off = 32; off; off >>= 1) v += __shfl_down(v, off);
  __syncthreads();
  if ((threadIdx.x & 63) == 0) sb[threadIdx.x >> 6] = v;
  __syncthreads();
  return (sb[0] + sb[1]) + (sb[2] + sb[3]);
}

// ---------------- RMSNorm row(1024) f32 -> bf16 ----------------
__global__ __launch_bounds__(256) void k_rms(const float* __restrict__ x, u16* __restrict__ o) {
  __shared__ float sb[4];
  int row = blockIdx.x, tid = threadIdx.x;
  float4 v = *(const float4*)&x[(size_t)row * 1024 + tid * 4];
  float s = bsum256(v.x * v.x + v.y * v.y + v.z * v.z + v.w * v.w, sb);
  float r = rsqrtf(s * (1.f / 1024.f) + 1e-6f);
  u16x4 ov;
  ov.x = f2b(v.x * r); ov.y = f2b(v.y * r); ov.z = f2b(v.z * r); ov.w = f2b(v.w * r);
  *(u16x4*)&o[(size_t)row * 1024 + tid * 4] = ov;
}

// ------- combine WO split-K partials + residual, emit x2 (f32) + rms -> bf16 -------
__global__ __launch_bounds__(256) void k_rms2c(const float* __restrict__ p,
                                               const float* __restrict__ x,
                                               float* __restrict__ x2,
                                               u16* __restrict__ xn) {
  __shared__ float sb[4];
  int row = blockIdx.x, tid = threadIdx.x;
  size_t base = (size_t)row * 1024 + tid * 4;
  float4 a = *(const float4*)&p[base];
  float4 c = *(const float4*)&p[(size_t)Mc * 1024 + base];
  float4 xv = *(const float4*)&x[base];
  float4 v;
  v.x = a.x + c.x + xv.x; v.y = a.y + c.y + xv.y;
  v.z = a.z + c.z + xv.z; v.w = a.w + c.w + xv.w;
  *(float4*)&x2[base] = v;
  float s = bsum256(v.x * v.x + v.y * v.y + v.z * v.z + v.w * v.w, sb);
  float r = rsqrtf(s * (1.f / 1024.f) + 1e-6f);
  u16x4 ov;
  ov.x = f2b(v.x * r); ov.y = f2b(v.y * r); ov.z = f2b(v.z * r); ov.w = f2b(v.w * r);
  *(u16x4*)&xn[base] = ov;
}

// ---------------- flash attention: 4 waves/block, 1024 blocks (4/CU) ----------------
#define MFMA16(A, B, C) __builtin_amdgcn_mfma_f32_16x16x32_bf16(A, B, C, 0, 0, 0)
__global__ __launch_bounds__(256) void k_attn(const u16* __restrict__ Q, const u16* __restrict__ Kb,
                                              const u16* __restrict__ VT, u16* __restrict__ O) {
  // XCD-grouped: XCD k gets wrk in [128k,128k+128) = 4 contiguous (b,h).
  // qb interleave (j&1 ? j/2 : 31-j/2): every 4 consecutive blocks sum to mean work.
  const int i = blockIdx.x;                 // 1024 blocks, all co-resident
  const int wrk = (i & 7) * 128 + (i >> 3);
  const int bh = wrk >> 5, j = wrk & 31;
  const int qb = (j & 1) ? (j >> 1) : (31 - (j >> 1));
  const int b = bh >> 4, h = bh & 15;
  const int tid = threadIdx.x, lane = tid & 63, w = tid >> 6;
  const int lr = lane & 15, lg = lane >> 4;
  const size_t TE = 2048ull * 1024ull;
  const u16* Qp = Q + (size_t)b * TE + (size_t)h * 64;
  const u16* Kp = Kb + (size_t)b * TE + (size_t)h * 64;
  const u16* Vp = VT + ((size_t)(b * 16 + h)) * 64ull * 2048ull;
  u16* Op = O + (size_t)b * TE + (size_t)h * 64;
  __shared__ __align__(16) u16 Ks[2][4096];   // [64 keys][64 d], swizzled chunks
  __shared__ __align__(16) u16 Vs[2][4096];   // [64 d][64 keys], swizzled chunks
  __shared__ __align__(16) u16 Ps[4][1024];   // per-wave P, frag-major
  auto stageKV = [&](int j0, int buf) {       // 4 gll16 per thread
    #pragma unroll
    for (int c = 0; c < 2; c++) {
      int u = c * 256 + tid;
      int row = u >> 3, slot = u & 7;
      int cg = slot ^ (row & 7);
      gll16(&Kp[(size_t)(j0 + row) * 1024 + cg * 8], &Ks[buf][u * 8]);
    }
    #pragma unroll
    for (int c = 0; c < 2; c++) {
      int u = c * 256 + tid;
      int row = u >> 3, slot = u & 7;
      int cg = slot ^ (row & 7);
      gll16(&Vp[(size_t)row * 2048 + j0 + cg * 8], &Vs[buf][u * 8]);
    }
  };
  const int q0 = qb * 64, qw0 = q0 + w * 16;
  bf16x8 qf0 = *(const bf16x8*)&Qp[(size_t)(qw0 + lr) * 1024 + lg * 8];
  bf16x8 qf1 = *(const bf16x8*)&Qp[(size_t)(qw0 + lr) * 1024 + 32 + lg * 8];
  f32x4 o0 = {}, o1 = {}, o2 = {}, o3 = {};
  float m = -1e30f, l = 0.f;
  const int NT = qb + 1;
  stageKV(0, 0);
  int cur = 0;
  for (int it = 0; it < NT; it++) {
    if (it + 1 < NT) {
      stageKV((it + 1) * 64, cur ^ 1);
      waitvm<4>();
    } else {
      waitvm<0>();
    }
    BARRIER();                               // all waves' cur staging landed
    const int j0 = it * 64;
    const u16* Kl = Ks[cur];
    const u16* Vl = Vs[cur];
    // QK^T (S^T trick: output key = j0+kg*16+lg*4+r, query = qw0+lr)
    f32x4 c4[4];
    __builtin_amdgcn_s_setprio(1);
    #pragma unroll
    for (int kg = 0; kg < 4; kg++) {
      f32x4 cc = {};
      int r = kg * 16 + lr;
      bf16x8 ka0 = *(const bf16x8*)&Kl[r * 64 + ((lg ^ (lr & 7)) * 8)];
      bf16x8 ka1 = *(const bf16x8*)&Kl[r * 64 + (((4 + lg) ^ (lr & 7)) * 8)];
      cc = MFMA16(ka0, qf0, cc);
      cc = MFMA16(ka1, qf1, cc);
      c4[kg] = cc;
    }
    __builtin_amdgcn_s_setprio(0);
    float xs[16];                            // UNSCALED scores
    #pragma unroll
    for (int kg = 0; kg < 4; kg++)
      #pragma unroll
      for (int r = 0; r < 4; r++) xs[kg * 4 + r] = c4[kg][r];
    if (it == NT - 1) {                      // diagonal tile: causal mask
      int q = qw0 + lr;
      #pragma unroll
      for (int kg = 0; kg < 4; kg++)
        #pragma unroll
        for (int r = 0; r < 4; r++)
          if (j0 + kg * 16 + lg * 4 + r > q) xs[kg * 4 + r] = -1e30f;
    }
    float tm = fmaxf(xs[0], xs[1]);
    tm = fmaxf(fmaxf(tm, xs[2]), xs[3]);
    tm = fmaxf(fmaxf(tm, xs[4]), xs[5]);
    tm = fmaxf(fmaxf(tm, xs[6]), xs[7]);
    tm = fmaxf(fmaxf(tm, xs[8]), xs[9]);
    tm = fmaxf(fmaxf(tm, xs[10]), xs[11]);
    tm = fmaxf(fmaxf(tm, xs[12]), xs[13]);
    tm = fmaxf(fmaxf(tm, xs[14]), xs[15]);
    tm = fmaxf(tm, __shfl_xor(tm, 16));
    tm = fmaxf(tm, __shfl_xor(tm, 32));      // per-query max
    if (!__all(tm <= m + 64.f)) {            // defer-max: rescale only on growth
      float mn = fmaxf(m, tm);
      float al = exp2f((m - mn) * C8);
      m = mn;
      l *= al;
      float ar0 = __shfl(al, lg * 4 + 0), ar1 = __shfl(al, lg * 4 + 1);
      float ar2 = __shfl(al, lg * 4 + 2), ar3 = __shfl(al, lg * 4 + 3);
      o0[0] *= ar0; o0[1] *= ar1; o0[2] *= ar2; o0[3] *= ar3;
      o1[0] *= ar0; o1[1] *= ar1; o1[2] *= ar2; o1[3] *= ar3;
      o2[0] *= ar0; o2[1] *= ar1; o2[2] *= ar2; o2[3] *= ar3;
      o3[0] *= ar0; o3[1] *= ar1; o3[2] *= ar2; o3[3] *= ar3;
    }
    const float mnC = -m * C8;
    float p[16], rs = 0.f;
    #pragma unroll
    for (int r = 0; r < 16; r++) { p[r] = exp2f(fmaf(xs[r], C8, mnC)); rs += p[r]; }
    rs += __shfl_xor(rs, 16);
    rs += __shfl_xor(rs, 32);
    l += rs;
    // write P (query row = lr, keys kg*16+lg*4..+3) via cvt_pk (2 f32/inst)
    #pragma unroll
    for (int kg = 0; kg < 4; kg++) {
      int unit = (kg >> 1) * 64 + ((kg & 1) * 2 + (lg >> 1)) * 16 + lr;
      uint2 pk;
      pk.x = cvtpk(p[kg * 4 + 0], p[kg * 4 + 1]);
      pk.y = cvtpk(p[kg * 4 + 2], p[kg * 4 + 3]);
      *(uint2*)&Ps[w][unit * 8 + (lg & 1) * 4] = pk;
    }
    bf16x8 pa0 = *(const bf16x8*)&Ps[w][(lg * 16 + lr) * 8];
    bf16x8 pa1 = *(const bf16x8*)&Ps[w][(64 + lg * 16 + lr) * 8];
    __builtin_amdgcn_s_setprio(1);
    #pragma unroll
    for (int dg = 0; dg < 4; dg++) {
      int dr = dg * 16 + lr;
      bf16x8 v0 = *(const bf16x8*)&Vl[dr * 64 + ((lg ^ (lr & 7)) * 8)];
      bf16x8 v1 = *(const bf16x8*)&Vl[dr * 64 + (((4 + lg) ^ (lr & 7)) * 8)];
      f32x4& od = (dg == 0) ? o0 : (dg == 1) ? o1 : (dg == 2) ? o2 : o3;
      od = MFMA16(pa0, v0, od);
      od = MFMA16(pa1, v1, od);
    }
    __builtin_amdgcn_s_setprio(0);
    BARRIER();                               // reads of buf[cur] done
    cur ^= 1;
  }
  float li0 = 1.f / __shfl(l, lg * 4 + 0), li1 = 1.f / __shfl(l, lg * 4 + 1);
  float li2 = 1.f / __shfl(l, lg * 4 + 2), li3 = 1.f / __shfl(l, lg * 4 + 3);
  #pragma unroll
  for (int r = 0; r < 4; r++) {
    float lir = (r == 0) ? li0 : (r == 1) ? li1 : (r == 2) ? li2 : li3;
    size_t ro = (size_t)(qw0 + lg * 4 + r) * 1024;
    Op[ro + lr]      = f2b(o0[r] * lir);
    Op[ro + 16 + lr] = f2b(o1[r] * lir);
    Op[ro + 32 + lr] = f2b(o2[r] * lir);
    Op[ro + 48 + lr] = f2b(o3[r] * lir);
  }
}

// ---------------- generic bf16 GEMM C = A(M,K) @ W(N,K)^T ----------------
// Coalesced gll16 staging, chunk-XOR swizzled LDS, double-buffered, counted-vmcnt.
// EPI: 0 = f32 (split-K via blockIdx.z); 3 = gate*acc+bias relu^2 -> bf16;
//      4 = gate*acc+bias + e4 -> f32; 8 = fused QKV (rotary q/k; V -> V^T direct);
//      9 = merged cq|h1 (f32 to Co / (float*)Cb).
template <int BM, int BN, int WR, int WC, int EPI>
__global__ __launch_bounds__(256) void gemm_bt(
    const u16* __restrict__ A, const u16* __restrict__ Bw,
    float* __restrict__ Co, u16* __restrict__ Cb, u16* __restrict__ Cb2, u16* __restrict__ Cb3,
    int gM, int N, int K, int KS,
    const float* __restrict__ e0, const float* __restrict__ e1,
    const float* __restrict__ e2, const float* __restrict__ e3,
    const float* __restrict__ e4) {
  constexpr int WM = BM / WR, WN = BN / WC;
  constexpr int FM = WM / 16, FN = WN / 16;
  constexpr int ACH = BM / 64, BCH = BN / 64;   // 16B units per thread per tile
  static_assert(WR * WC == 4 && BM % 64 == 0 && BN % 64 == 0, "cfg");
  __shared__ __align__(16) u16 As[2][BM * 32];
  __shared__ __align__(16) u16 Bs[2][BN * 32];
  const int tid = threadIdx.x;
  const int lane = tid & 63, wid = tid >> 6;
  const int wr = wid / WC, wc = wid % WC;
  const int bm = blockIdx.y * BM, bn = blockIdx.x * BN;
  const int lr = lane & 15, lg = lane >> 4;
  const int arow0 = bm + wr * WM, bcol0 = bn + wc * WN;
  const int kbeg = blockIdx.z * KS, kend = kbeg + KS;
  f32x4 acc[FM][FN] = {};
  auto stage = [&](int k0, int buf) {
    #pragma unroll
    for (int c = 0; c < ACH; c++) {
      int u = c * 256 + tid;
      int row = u >> 2, slot = u & 3;
      int cg = slot ^ (row & 3) ^ ((row >> 2) & 3);
      gll16(&A[(size_t)(bm + row) * K + k0 + cg * 8], &As[buf][u * 8]);
    }
    #pragma unroll
    for (int c = 0; c < BCH; c++) {
      int u = c * 256 + tid;
      int row = u >> 2, slot = u & 3;
      int cg = slot ^ (row & 3) ^ ((row >> 2) & 3);
      gll16(&Bw[(size_t)(bn + row) * K + k0 + cg * 8], &Bs[buf][u * 8]);
    }
  };
  stage(kbeg, 0);
  int cur = 0;
  for (int k0 = kbeg; k0 < kend; k0 += 32) {
    if (k0 + 32 < kend) {
      stage(k0 + 32, cur ^ 1);     // issue next tile FIRST, wait only for cur
      waitvm<ACH + BCH>();
    } else {
      waitvm<0>();
    }
    BARRIER();                      // cur staging visible to all waves
    const u16* Ab = As[cur];
    const u16* Bb = Bs[cur];
    bf16x8 af[FM], bfr[FN];
    #pragma unroll
    for (int i = 0; i < FM; i++) {
      int tr = wr * WM + i * 16 + lr;
      af[i] = *(const bf16x8*)&Ab[tr * 32 + ((lg ^ (tr & 3) ^ ((tr >> 2) & 3)) * 8)];
    }
    #pragma unroll
    for (int j = 0; j < FN; j++) {
      int tr = wc * WN + j * 16 + lr;
      bfr[j] = *(const bf16x8*)&Bb[tr * 32 + ((lg ^ (tr & 3) ^ ((tr >> 2) & 3)) * 8)];
    }
    #pragma unroll
    for (int i = 0; i < FM; i++)
      #pragma unroll
      for (int j = 0; j < FN; j++)
        acc[i][j] = __builtin_amdgcn_mfma_f32_16x16x32_bf16(af[i], bfr[j], acc[i][j], 0, 0, 0);
    BARRIER();                      // all reads of cur done before next overwrite
    cur ^= 1;
  }
  const int nb0 = bcol0 + lr;
  if constexpr (EPI == 0) {
    float* Cz = Co + (size_t)blockIdx.z * ((size_t)gM * N);
    #pragma unroll
    for (int i = 0; i < FM; i++)
      #pragma unroll
      for (int r = 0; r < 4; r++) {
        size_t mrow = (size_t)(arow0 + i * 16 + lg * 4 + r);
        #pragma unroll
        for (int j = 0; j < FN; j++)
          Cz[mrow * N + nb0 + j * 16] = acc[i][j][r];
      }
  } else if constexpr (EPI == 9) {
    // merged cq|h1: bn==0 -> cq (f32, stride 64); else h1 (f32, stride 256)
    if (bn == 0) {
      #pragma unroll
      for (int i = 0; i < FM; i++)
        #pragma unroll
        for (int r = 0; r < 4; r++) {
          size_t mrow = (size_t)(arow0 + i * 16 + lg * 4 + r);
          #pragma unroll
          for (int j = 0; j < FN; j++)
            Co[mrow * 64 + nb0 + j * 16] = acc[i][j][r];
        }
    } else {
      float* H = (float*)Cb;
      const int c0 = bcol0 - 64 + lr;
      #pragma unroll
      for (int i = 0; i < FM; i++)
        #pragma unroll
        for (int r = 0; r < 4; r++) {
          size_t mrow = (size_t)(arow0 + i * 16 + lg * 4 + r);
          #pragma unroll
          for (int j = 0; j < FN; j++)
            H[mrow * 256 + c0 + j * 16] = acc[i][j][r];
        }
    }
  } else if constexpr (EPI == 8) {
    // fused QKV; requires WN==64 (wave covers one head). V goes to V^T directly.
    if (bn < 2048) {
      u16* dst = (bn < 1024) ? Cb : Cb2;
      const int nq0 = (bcol0 & 1023) + lr;
      #pragma unroll
      for (int i = 0; i < FM; i++)
        #pragma unroll
        for (int r = 0; r < 4; r++) {
          size_t mrow = (size_t)(arow0 + i * 16 + lg * 4 + r);
          int t = (int)(mrow & 2047);
          #pragma unroll
          for (int j = 0; j < 2; j++) {
            int d = lr + j * 16;
            float cth = e0[t * 32 + d], sth = e1[t * 32 + d];
            float x1 = acc[i][j][r], x2 = acc[i][j + 2][r];
            dst[mrow * 1024 + nq0 + j * 16]       = f2b(x1 * cth + x2 * sth);
            dst[mrow * 1024 + nq0 + (j + 2) * 16] = f2b(x2 * cth - x1 * sth);
          }
        }
    } else {
      // V^T[(b*16+h)*64 + d][t]; per (i,j) the 4 r-values are 4 consecutive t
      const int hh = (bcol0 - 2048) >> 6;
      const int bb = arow0 >> 11;
      const int t0 = (arow0 & 2047) + lg * 4;
      u16* vt = Cb3 + ((size_t)(bb * 16 + hh) * 64) * 2048;
      #pragma unroll
      for (int i = 0; i < FM; i++)
        #pragma unroll
        for (int j = 0; j < FN; j++) {
          u16x4 pk;
          pk.x = f2b(acc[i][j][0]); pk.y = f2b(acc[i][j][1]);
          pk.z = f2b(acc[i][j][2]); pk.w = f2b(acc[i][j][3]);
          *(u16x4*)&vt[(size_t)(lr + j * 16) * 2048 + t0 + i * 16] = pk;
        }
    }
  } else {
    // EPI 3/4: gate_out = 1+tanh(ogs*d) = 2/(1+exp2(ogs*d*NEG2LOG2E))
    const float cg = e3[0] * NEG2LOG2E;
    float gB[FN][8], bias[FN];
    #pragma unroll
    for (int j = 0; j < FN; j++) {
      int n = nb0 + j * 16;
      bias[j] = e2[n];
      #pragma unroll
      for (int rr = 0; rr < 8; rr++) gB[j][rr] = e1[(size_t)rr * N + n];
    }
    #pragma unroll
    for (int i = 0; i < FM; i++)
      #pragma unroll
      for (int r = 0; r < 4; r++) {
        size_t mrow = (size_t)(arow0 + i * 16 + lg * 4 + r);
        float go8[8];
        #pragma unroll
        for (int rr = 0; rr < 8; rr++) go8[rr] = e0[mrow * 8 + rr];
        #pragma unroll
        for (int j = 0; j < FN; j++) {
          float d = 0.f;
          #pragma unroll
          for (int rr = 0; rr < 8; rr++) d += go8[rr] * gB[j][rr];
          float gate = 2.f * __builtin_amdgcn_rcpf(1.f + exp2f(cg * d));
          float v = acc[i][j][r] * gate + bias[j];
          if constexpr (EPI == 3) {
            v = fmaxf(v, 0.f); v *= v;
            Cb[mrow * N + nb0 + j * 16] = f2b(v);
          } else {
            v += e4[mrow * N + nb0 + j * 16];
            Co[mrow * N + nb0 + j * 16] = v;
          }
        }
      }
  }
}

// -------- fused ctx + gate1(+LN1 -> A1 direct) + gate2 (-> gb2, go2) --------
__global__ __launch_bounds__(256) void k_ctxgate(
    const float* __restrict__ cq, const float* __restrict__ pr,
    const float* __restrict__ h1, const float* __restrict__ lg1,
    const float* __restrict__ lb1,
    const float* __restrict__ f_m1w, const float* __restrict__ f_m1b,
    const float* __restrict__ f_m2w, const float* __restrict__ f_m2b,
    const float* __restrict__ f_ogw, const float* __restrict__ f_ogb,
    const float* __restrict__ p_m1w, const float* __restrict__ p_m1b,
    const float* __restrict__ p_m2w, const float* __restrict__ p_m2b,
    const float* __restrict__ p_ogw, const float* __restrict__ p_ogb,
    u16* __restrict__ a1, float* __restrict__ go1,
    float* __restrict__ gb2, float* __restrict__ go2) {
  __shared__ float pl[64 * 65];               // protos; reused as hs[16][256]
  __shared__ __align__(16) float cqs[16][64];
  __shared__ float wl[16][64];
  __shared__ __align__(16) float cs[16][64];
  __shared__ __align__(16) float gls[16][128];
  __shared__ float sLN[16][2];
  const int tid = threadIdx.x;
  const int row0 = blockIdx.x * 16;
  for (int idx = tid; idx < 4096; idx += 256) pl[(idx >> 6) * 65 + (idx & 63)] = pr[idx];
  for (int idx = tid; idx < 1024; idx += 256)
    cqs[idx >> 6][idx & 63] = cq[(size_t)row0 * 64 + idx];
  __syncthreads();
  // scores + softmax(64): thread = (row, pg); protos p = pg*4..+3
  const int row = tid >> 4, pg = tid & 15;
  float sc[4];
  #pragma unroll
  for (int q = 0; q < 4; q++) {
    int p = pg * 4 + q;
    float s = 0.f;
    #pragma unroll
    for (int k4 = 0; k4 < 16; k4++) {
      float4 cv = *(const float4*)&cqs[row][k4 * 4];
      const float* pw = &pl[p * 65 + k4 * 4];
      s += cv.x * pw[0] + cv.y * pw[1] + cv.z * pw[2] + cv.w * pw[3];
    }
    sc[q] = s * 0.125f;
  }
  float mx = fmaxf(fmaxf(sc[0], sc[1]), fmaxf(sc[2], sc[3]));
  #pragma unroll
  for (int off = 1; off <= 8; off <<= 1) mx = fmaxf(mx, __shfl_xor(mx, off));
  float e[4], sum = 0.f;
  #pragma unroll
  for (int q = 0; q < 4; q++) { e[q] = __expf(sc[q] - mx); sum += e[q]; }
  #pragma unroll
  for (int off = 1; off <= 8; off <<= 1) sum += __shfl_xor(sum, off);
  float inv = 1.f / sum;
  #pragma unroll
  for (int q = 0; q < 4; q++) wl[row][pg * 4 + q] = e[q] * inv;
  __syncthreads();
  #pragma unroll
  for (int q = 0; q < 4; q++) {
    int c = pg * 4 + q;
    float a = 0.f;
    for (int p = 0; p < 64; p++) a += wl[row][p] * pl[p * 65 + c];
    cs[row][c] = a;
  }
  __syncthreads();                 // cs done; pl (protos) now dead
  // ---- load h1 tile into pl region; per-row LN stats ----
  float* hs = pl;
  for (int idx = tid; idx < 4096; idx += 256)
    hs[idx] = h1[(size_t)row0 * 256 + idx];
  __syncthreads();
  {
    int r = tid >> 4, sub = tid & 15;
    float s = 0.f, s2 = 0.f;
    #pragma unroll
    for (int k = 0; k < 16; k++) {
      float v = hs[r * 256 + sub * 16 + k];
      s += v; s2 += v * v;
    }
    #pragma unroll
    for (int mk = 1; mk <= 8; mk <<= 1) { s += __shfl_xor(s, mk); s2 += __shfl_xor(s2, mk); }
    if (sub == 0) {
      float mu = s * (1.f / 256.f);
      sLN[r][0] = mu;
      sLN[r][1] = rsqrtf(fmaxf(s2 * (1.f / 256.f) - mu * mu, 0.f) + 1e-5f);
    }
  }
  __syncthreads();
  // ---- gate 1: m1+gelu -> gls; og -> go1; m2 -> sigmoid; A1 = LN(h1)*gb ----
  for (int idx = tid; idx < 2048; idx += 256) {
    int r = idx >> 7, mh = idx & 127;
    const float* wrow = &f_m1w[(size_t)mh * 64];
    float a = f_m1b[mh];
    #pragma unroll
    for (int k4 = 0; k4 < 16; k4++) {
      float4 w4 = *(const float4*)&wrow[k4 * 4];
      float4 c4v = *(const float4*)&cs[r][k4 * 4];
      a += c4v.x * w4.x + c4v.y * w4.y + c4v.z * w4.z + c4v.w * w4.w;
    }
    gls[r][mh] = 0.5f * a * (1.f + erff(a * 0.70710678f));
  }
  if (tid < 128) {
    int r = tid >> 3, rr = tid & 7;
    const float* wrow = &f_ogw[(size_t)rr * 64];
    float a = f_ogb[rr];
    #pragma unroll
    for (int k4 = 0; k4 < 16; k4++) {
      float4 w4 = *(const float4*)&wrow[k4 * 4];
      float4 c4v = *(const float4*)&cs[r][k4 * 4];
      a += c4v.x * w4.x + c4v.y * w4.y + c4v.z * w4.z + c4v.w * w4.w;
    }
    go1[(size_t)(row0 + r) * 8 + rr] = a;
  }
  __syncthreads();
  {
    int n = tid;
    float acc2[16];
    #pragma unroll
    for (int r = 0; r < 16; r++) acc2[r] = f_m2b[n];
    for (int k4 = 0; k4 < 32; k4++) {
      float4 wv = *(const float4*)&f_m2w[(size_t)n * 128 + k4 * 4];
      #pragma unroll
      for (int r = 0; r < 16; r++) {
        float4 g = *(const float4*)&gls[r][k4 * 4];
        acc2[r] += g.x * wv.x + g.y * wv.y + g.z * wv.z + g.w * wv.w;
      }
    }
    float gvn = lg1[n], bvn = lb1[n];
    #pragma unroll
    for (int r = 0; r < 16; r++) {
      float sig = 1.f / (1.f + __expf(-acc2[r]));
      float y = (hs[r * 256 + n] - sLN[r][0]) * sLN[r][1] * gvn + bvn;
      a1[(size_t)(row0 + r) * 256 + n] = f2b(y * sig);
    }
  }
  __syncthreads();
  // ---- gate 2 -> gb2, go2 ----
  for (int idx = tid; idx < 2048; idx += 256) {
    int r = idx >> 7, mh = idx & 127;
    const float* wrow = &p_m1w[(size_t)mh * 64];
    float a = p_m1b[mh];
    #pragma unroll
    for (int k4 = 0; k4 < 16; k4++) {
      float4 w4 = *(const float4*)&wrow[k4 * 4];
      float4 c4v = *(const float4*)&cs[r][k4 * 4];
      a += c4v.x * w4.x + c4v.y * w4.y + c4v.z * w4.z + c4v.w * w4.w;
    }
    gls[r][mh] = 0.5f * a * (1.f + erff(a * 0.70710678f));
  }
  if (tid < 128) {
    int r = tid >> 3, rr = tid & 7;
    const float* wrow = &p_ogw[(size_t)rr * 64];
    float a = p_ogb[rr];
    #pragma unroll
    for (int k4 = 0; k4 < 16; k4++) {
      float4 w4 = *(const float4*)&wrow[k4 * 4];
      float4 c4v = *(const float4*)&cs[r][k4 * 4];
      a += c4v.x * w4.x + c4v.y * w4.y + c4v.z * w4.z + c4v.w * w4.w;
    }
    go2[(size_t)(row0 + r) * 8 + rr] = a;
  }
  __syncthreads();
  {
    int n = tid;
    float acc2[16];
    #pragma unroll
    for (int r = 0; r < 16; r++) acc2[r] = p_m2b[n];
    for (int k4 = 0; k4 < 32; k4++) {
      float4 wv = *(const float4*)&p_m2w[(size_t)n * 128 + k4 * 4];
      #pragma unroll
      for (int r = 0; r < 16; r++) {
        float4 g = *(const float4*)&gls[r][k4 * 4];
        acc2[r] += g.x * wv.x + g.y * wv.y + g.z * wv.z + g.w * wv.w;
      }
    }
    #pragma unroll
    for (int r = 0; r < 16; r++)
      gb2[(size_t)(row0 + r) * 256 + n] = 1.f / (1.f + __expf(-acc2[r]));
  }
}

// ---------------- LN(row 256) over summed splits * gate_basis -> bf16 ----------------
template <int NS>
__global__ __launch_bounds__(256) void k_lnmul(const float* __restrict__ h,
                                               const float* __restrict__ g,
                                               const float* __restrict__ b,
                                               const float* __restrict__ gbm,
                                               u16* __restrict__ o) {
  __shared__ float sb[4];
  int row = blockIdx.x, n = threadIdx.x;
  float x = 0.f;
  #pragma unroll
  for (int z = 0; z < NS; z++) x += h[(size_t)z * Mc * 256 + (size_t)row * 256 + n];
  float mu = bsum256(x, sb) * (1.f / 256.f);
  float d = x - mu;
  float var = bsum256(d * d, sb) * (1.f / 256.f);
  float y = d * rsqrtf(var + 1e-5f) * g[n] + b[n];
  o[(size_t)row * 256 + n] = f2b(y * gbm[(size_t)row * 256 + n]);
}

// ---------------- host launch ----------------
extern "C" void kernel_launch(void* const* d_in, const int* in_sizes, int n_in,
                              void* d_out, int out_size, void* d_ws, size_t ws_size,
                              hipStream_t stream) {
  (void)in_sizes; (void)n_in; (void)out_size; (void)ws_size;
  const float* x      = (const float*)d_in[0];
  const float* cosb   = (const float*)d_in[1];
  const float* sinb   = (const float*)d_in[2];
  const float* wq     = (const float*)d_in[3];
  const float* wk     = (const float*)d_in[4];
  const float* wv     = (const float*)d_in[5];
  const float* wo     = (const float*)d_in[6];
  const float* cb_qw  = (const float*)d_in[7];
  const float* protos = (const float*)d_in[8];
  const float* fc_bw  = (const float*)d_in[9];
  const float* fc_lg  = (const float*)d_in[10];
  const float* fc_lb  = (const float*)d_in[11];
  const float* fc_tm  = (const float*)d_in[12];
  const float* fc_b   = (const float*)d_in[13];
  const float* fc_m1w = (const float*)d_in[14];
  const float* fc_m1b = (const float*)d_in[15];
  const float* fc_m2w = (const float*)d_in[16];
  const float* fc_m2b = (const float*)d_in[17];
  const float* fc_ogw = (const float*)d_in[18];
  const float* fc_ogb = (const float*)d_in[19];
  const float* fc_ogB = (const float*)d_in[20];
  const float* fc_ogs = (const float*)d_in[21];
  const float* pj_bw  = (const float*)d_in[22];
  const float* pj_lg  = (const float*)d_in[23];
  const float* pj_lb  = (const float*)d_in[24];
  const float* pj_tm  = (const float*)d_in[25];
  const float* pj_b   = (const float*)d_in[26];
  const float* pj_m1w = (const float*)d_in[27];
  const float* pj_m1b = (const float*)d_in[28];
  const float* pj_m2w = (const float*)d_in[29];
  const float* pj_m2b = (const float*)d_in[30];
  const float* pj_ogw = (const float*)d_in[31];
  const float* pj_ogb = (const float*)d_in[32];
  const float* pj_ogB = (const float*)d_in[33];
  const float* pj_ogs = (const float*)d_in[34];
  char* ws = (char*)d_ws;
  float* outp = (float*)d_out;
  auto U = [&](size_t o) { return (u16*)(ws + o); };
  auto F = [&](size_t o) { return (float*)(ws + o); };
  const float* nf = nullptr;
  u16* nu = nullptr;

  // 0) merged weight conversions
  {
    Cvt9 a;
    const float* srcs[9] = {wq, wk, wv, wo, cb_qw, fc_bw, fc_tm, pj_bw, pj_tm};
    size_t offs[9] = {O_WQ, O_WK, O_WV, O_WO, O_CBQ, O_FCBW, O_FCTM, O_PJBW, O_PJTM};
    int ns[9] = {Ec*Ec, Ec*Ec, Ec*Ec, Ec*Ec, Cc*Ec, BFc*Ec, F4c*BFc, BFc*F4c, Ec*BFc};
    int cum = 0;
    for (int s = 0; s < 9; s++) {
      a.s[s] = srcs[s]; a.d[s] = U(offs[s]); a.cum[s] = cum; cum += ns[s] / 4;
    }
    a.cum[9] = cum;
    k_cvt<<<dim3(cum / 256), dim3(256), 0, stream>>>(a);
  }
  // 1) xn = rms(x)
  k_rms<<<dim3(Mc), dim3(256), 0, stream>>>(x, U(O_XN));
  // 2) fused QKV projection: rotary q/k -> QB/KB; v -> V^T direct
  gemm_bt<128,128,2,2,8><<<dim3(24,32), dim3(256), 0, stream>>>(U(O_XN), U(O_WQ), nullptr, U(O_QB), U(O_KB), U(O_VT), Mc, 3072, Ec, Ec, cosb, sinb, nf, nf, nf);
  // 3) attention -> bf16 (reuses XN region); 1024 blocks, 4/CU
  k_attn<<<dim3(1024), dim3(256), 0, stream>>>(U(O_QB), U(O_KB), U(O_VT), U(O_XN));
  // 4) wo projection split-K x2 -> partials
  gemm_bt<128,128,2,2,0><<<dim3(8,32,2), dim3(256), 0, stream>>>(U(O_XN), U(O_WO), F(O_WOP), nu, nu, nu, Mc, Ec, Ec, 512, nf, nf, nf, nf, nf);
  // 5) x2 = p0+p1+x (f32 out) ; xn2 = rms(x2)
  k_rms2c<<<dim3(Mc), dim3(256), 0, stream>>>(F(O_WOP), x, F(O_X2), U(O_XN));
  // 6) merged cq|h1 GEMM: B = [cb_qw ; fc_bw] (contiguous, N=320)
  gemm_bt<64,64,1,4,9><<<dim3(5,64), dim3(256), 0, stream>>>(U(O_XN), U(O_CBQ), F(O_CQ), (u16*)F(O_H1), nu, nu, Mc, 320, Ec, Ec, nf, nf, nf, nf, nf);
  // 7) fused ctx + gate1(+LN1 -> A1) + gate2 (-> gb2, go2)
  k_ctxgate<<<dim3(Mc / 16), dim3(256), 0, stream>>>(F(O_CQ), protos,
      F(O_H1), fc_lg, fc_lb,
      fc_m1w, fc_m1b, fc_m2w, fc_m2b, fc_ogw, fc_ogb,
      pj_m1w, pj_m1b, pj_m2w, pj_m2b, pj_ogw, pj_ogb,
      U(O_A1), F(O_GO1), F(O_GB2), F(O_GO2));
  // 8) h = relu^2(gated fc_tm GEMM)
  gemm_bt<128,128,2,2,3><<<dim3(32,32), dim3(256), 0, stream>>>(U(O_A1), U(O_FCTM), nullptr, U(O_HBF), nu, nu, Mc, F4c, BFc, BFc, F(O_GO1), fc_ogB, fc_b, fc_ogs, nf);
  // 9) pj: h2 = h @ pj_bw.T (64x64, split-K x4); A2 = LN(h2)*gb2
  gemm_bt<64,64,1,4,0><<<dim3(4,64,4), dim3(256), 0, stream>>>(U(O_HBF), U(O_PJBW), F(O_H2), nu, nu, nu, Mc, BFc, F4c, 1024, nf, nf, nf, nf, nf);
  k_lnmul<4><<<dim3(Mc), dim3(256), 0, stream>>>(F(O_H2), pj_lg, pj_lb, F(O_GB2), U(O_A2));
  // 10) out = gated pj_tm GEMM + x2
  gemm_bt<128,128,2,2,4><<<dim3(8,32), dim3(256), 0, stream>>>(U(O_A2), U(O_PJTM), outp, nu, nu, nu, Mc, Ec, BFc, BFc, F(O_GO2), pj_ogB, pj_b, pj_ogs, F(O_X2));
}

// Round 9
// 405.883 us; speedup vs baseline: 1.0458x; 1.0458x over previous
//
// RemixedBlock fused forward — MI355X gfx950, round 9.
// Changes vs r8: attention reverted to r7 paired 512-block grid (r8's 4/CU
// experiment measured 43% per-unit slowdown); pj_tm retiled 64x64 (4 blocks/CU
// at K=256). Keeps r8's V^T-direct QKV epilogue, ctxgate+LN1 fusion,
// WO split-K + fused rms2c.
#include <hip/hip_runtime.h>
#include <hip/hip_bf16.h>

typedef unsigned short u16;
typedef unsigned int u32;
typedef __attribute__((ext_vector_type(8))) short bf16x8;
typedef __attribute__((ext_vector_type(4))) float f32x4;
typedef __attribute__((ext_vector_type(4))) u16 u16x4;

#define DEVFN __device__ __forceinline__

DEVFN u16 f2b(float f) {                    // f32 -> bf16 RNE
  u32 u = __builtin_bit_cast(u32, f);
  return (u16)((u + 0x7FFFu + ((u >> 16) & 1u)) >> 16);
}
DEVFN float b2f(u16 b) { return __builtin_bit_cast(float, (u32)b << 16); }
DEVFN u32 cvtpk(float lo, float hi) {       // packs 2 f32 -> 2 bf16 in one inst
  u32 r;
  asm("v_cvt_pk_bf16_f32 %0, %1, %2" : "=v"(r) : "v"(lo), "v"(hi));
  return r;
}

DEVFN void gll16(const void* g, void* l) {  // 16B global->LDS direct (dwordx4)
  __builtin_amdgcn_global_load_lds((const __attribute__((address_space(1))) void*)g,
                                   (__attribute__((address_space(3))) void*)l, 16, 0, 0);
}
#define BARRIER() __builtin_amdgcn_s_barrier()

template <int N> DEVFN void waitvm() {      // s_waitcnt vmcnt(N), compile-time N
  if constexpr (N == 0) asm volatile("s_waitcnt vmcnt(0)" ::: "memory");
  else if constexpr (N == 1) asm volatile("s_waitcnt vmcnt(1)" ::: "memory");
  else if constexpr (N == 2) asm volatile("s_waitcnt vmcnt(2)" ::: "memory");
  else if constexpr (N == 3) asm volatile("s_waitcnt vmcnt(3)" ::: "memory");
  else if constexpr (N == 4) asm volatile("s_waitcnt vmcnt(4)" ::: "memory");
  else if constexpr (N == 5) asm volatile("s_waitcnt vmcnt(5)" ::: "memory");
  else if constexpr (N == 6) asm volatile("s_waitcnt vmcnt(6)" ::: "memory");
  else asm volatile("s_waitcnt vmcnt(8)" ::: "memory");
}

// ---- problem dims ----
constexpr int Tc = 2048, Ec = 1024, Hc = 16, Cc = 64, BFc = 256, F4c = 4096;
constexpr int Mc = 2 * Tc;  // 4096 rows
constexpr float C8 = 0.18033688f;   // log2(e)/8  (folds 1/sqrt(64) and ln->log2)
constexpr float NEG2LOG2E = -2.8853901f;  // 1+tanh(y)=2/(1+exp2(y*NEG2LOG2E))

// ---- workspace layout (bytes); lifetimes strictly sequential per region ----
constexpr size_t MB = 1ull << 20;
constexpr size_t O_XN  = 0;                    // 8MB bf16: xn -> attn_out -> xn2
constexpr size_t O_HBF = 8 * MB;               // 32MB bf16 relu^2 out (spans 8-40)
constexpr size_t O_QB  = 40 * MB;              // 8MB q bf16 (rotary applied)
constexpr size_t O_WOP = 40 * MB;              // 2x16MB WO split-K partials (after QB/KB dead)
constexpr size_t O_H1  = 40 * MB;              // 4MB h1 f32 (after WOP dead)
constexpr size_t O_A2  = 45 * MB;              // 2MB bf16
constexpr size_t O_KB  = 48 * MB;              // 8MB k bf16
constexpr size_t O_H2  = 48 * MB;              // 4x4MB h2 partials (after KB/WOP dead)
constexpr size_t O_CQ  = 64 * MB;              // 1MB cq f32
constexpr size_t O_GO1 = 68 * MB + 512 * 1024; // 128KB
constexpr size_t O_GO2 = 68 * MB + 640 * 1024; // 128KB
constexpr size_t O_VT  = 72 * MB;              // 8MB V^T bf16 (B,H,D,T)
constexpr size_t O_GB2 = 73 * MB;              // 4MB (after VT dead)
constexpr size_t O_A1  = 77 * MB;              // 2MB bf16 (after VT dead)
constexpr size_t O_X2  = 80 * MB;              // 16MB f32 residual
constexpr size_t O_WQ  = 96 * MB, O_WK = 98 * MB, O_WV = 100 * MB, O_WO = 102 * MB;
constexpr size_t O_CBQ = 104 * MB;             // cb_qw bf16 (64x1024, 128KB)
constexpr size_t O_FCBW = O_CBQ + 128 * 1024;  // fc_bw bf16 CONTIGUOUS after cbq
constexpr size_t O_FCTM = 105 * MB;
constexpr size_t O_PJBW = 107 * MB;
constexpr size_t O_PJTM = 109 * MB;            // ends 109.5MB

// ---------------- merged f32->bf16 conversions (9 segments) ----------------
struct Cvt9 {
  const float* s[9];
  u16* d[9];
  int cum[10];   // in 4-element units
};
__global__ __launch_bounds__(256) void k_cvt(Cvt9 a) {
  int i = blockIdx.x * 256 + threadIdx.x;   // unit of 4 elements (grid exact)
  int seg = 0;
  #pragma unroll
  for (int s = 1; s < 9; s++) seg += (i >= a.cum[s]);
  int off = i - a.cum[seg];
  float4 v = *(const float4*)&a.s[seg][(size_t)off * 4];
  u16x4 o; o.x = f2b(v.x); o.y = f2b(v.y); o.z = f2b(v.z); o.w = f2b(v.w);
  *(u16x4*)&a.d[seg][(size_t)off * 4] = o;
}

// ---------------- block reduction helper (256 threads) ----------------
DEVFN float bsum256(float v, float* sb) {
  #pragma unroll
  for (int off = 32; off; off >>= 1) v += __shfl_down(v, off);
  __syncthreads();
  if ((threadIdx.x & 63) == 0) sb[threadIdx.x >> 6] = v;
  __syncthreads();
  return (sb[0] + sb[1]) + (sb[2] + sb[3]);
}

// ---------------- RMSNorm row(1024) f32 -> bf16 ----------------
__global__ __launch_bounds__(256) void k_rms(const float* __restrict__ x, u16* __restrict__ o) {
  __shared__ float sb[4];
  int row = blockIdx.x, tid = threadIdx.x;
  float4 v = *(const float4*)&x[(size_t)row * 1024 + tid * 4];
  float s = bsum256(v.x * v.x + v.y * v.y + v.z * v.z + v.w * v.w, sb);
  float r = rsqrtf(s * (1.f / 1024.f) + 1e-6f);
  u16x4 ov;
  ov.x = f2b(v.x * r); ov.y = f2b(v.y * r); ov.z = f2b(v.z * r); ov.w = f2b(v.w * r);
  *(u16x4*)&o[(size_t)row * 1024 + tid * 4] = ov;
}

// ------- combine WO split-K partials + residual, emit x2 (f32) + rms -> bf16 -------
__global__ __launch_bounds__(256) void k_rms2c(const float* __restrict__ p,
                                               const float* __restrict__ x,
                                               float* __restrict__ x2,
                                               u16* __restrict__ xn) {
  __shared__ float sb[4];
  int row = blockIdx.x, tid = threadIdx.x;
  size_t base = (size_t)row * 1024 + tid * 4;
  float4 a = *(const float4*)&p[base];
  float4 c = *(const float4*)&p[(size_t)Mc * 1024 + base];
  float4 xv = *(const float4*)&x[base];
  float4 v;
  v.x = a.x + c.x + xv.x; v.y = a.y + c.y + xv.y;
  v.z = a.z + c.z + xv.z; v.w = a.w + c.w + xv.w;
  *(float4*)&x2[base] = v;
  float s = bsum256(v.x * v.x + v.y * v.y + v.z * v.z + v.w * v.w, sb);
  float r = rsqrtf(s * (1.f / 1024.f) + 1e-6f);
  u16x4 ov;
  ov.x = f2b(v.x * r); ov.y = f2b(v.y * r); ov.z = f2b(v.z * r); ov.w = f2b(v.w * r);
  *(u16x4*)&xn[base] = ov;
}

// ---------------- flash attention: 4 waves/block, paired 64-q tiles (r7) ----------------
#define MFMA16(A, B, C) __builtin_amdgcn_mfma_f32_16x16x32_bf16(A, B, C, 0, 0, 0)
__global__ __launch_bounds__(256) void k_attn(const u16* __restrict__ Q, const u16* __restrict__ Kb,
                                              const u16* __restrict__ VT, u16* __restrict__ O) {
  // XCD-grouped decode: natural id i -> XCD i%8; give each XCD 4 contiguous (h,b)
  const int i = blockIdx.x;                 // 512 blocks
  const int wrk = (i & 7) * 64 + (i >> 3);
  const int hb = wrk >> 4, xp = wrk & 15;
  const int b = hb >> 4, h = hb & 15;
  const int tid = threadIdx.x, lane = tid & 63, w = tid >> 6;
  const int lr = lane & 15, lg = lane >> 4;
  const size_t TE = 2048ull * 1024ull;
  const u16* Qp = Q + (size_t)b * TE + (size_t)h * 64;
  const u16* Kp = Kb + (size_t)b * TE + (size_t)h * 64;
  const u16* Vp = VT + ((size_t)(b * 16 + h)) * 64ull * 2048ull;
  u16* Op = O + (size_t)b * TE + (size_t)h * 64;
  __shared__ __align__(16) u16 Ks[2][4096];   // [64 keys][64 d], swizzled chunks
  __shared__ __align__(16) u16 Vs[2][4096];   // [64 d][64 keys], swizzled chunks
  __shared__ __align__(16) u16 Ps[4][1024];   // per-wave P, frag-major
  auto stageKV = [&](int j0, int buf) {       // 4 gll16 per thread
    #pragma unroll
    for (int c = 0; c < 2; c++) {
      int u = c * 256 + tid;
      int row = u >> 3, slot = u & 7;
      int cg = slot ^ (row & 7);
      gll16(&Kp[(size_t)(j0 + row) * 1024 + cg * 8], &Ks[buf][u * 8]);
    }
    #pragma unroll
    for (int c = 0; c < 2; c++) {
      int u = c * 256 + tid;
      int row = u >> 3, slot = u & 7;
      int cg = slot ^ (row & 7);
      gll16(&Vp[(size_t)row * 2048 + j0 + cg * 8], &Vs[buf][u * 8]);
    }
  };
  auto run_tile = [&](int qb) {
    const int q0 = qb * 64, qw0 = q0 + w * 16;
    bf16x8 qf0 = *(const bf16x8*)&Qp[(size_t)(qw0 + lr) * 1024 + lg * 8];
    bf16x8 qf1 = *(const bf16x8*)&Qp[(size_t)(qw0 + lr) * 1024 + 32 + lg * 8];
    f32x4 o0 = {}, o1 = {}, o2 = {}, o3 = {};
    float m = -1e30f, l = 0.f;
    const int NT = qb + 1;
    stageKV(0, 0);
    int cur = 0;
    for (int it = 0; it < NT; it++) {
      if (it + 1 < NT) {
        stageKV((it + 1) * 64, cur ^ 1);
        waitvm<4>();
      } else {
        waitvm<0>();
      }
      BARRIER();                               // all waves' cur staging landed
      const int j0 = it * 64;
      const u16* Kl = Ks[cur];
      const u16* Vl = Vs[cur];
      // QK^T (S^T trick: output key = j0+kg*16+lg*4+r, query = qw0+lr)
      f32x4 c4[4];
      __builtin_amdgcn_s_setprio(1);
      #pragma unroll
      for (int kg = 0; kg < 4; kg++) {
        f32x4 cc = {};
        int r = kg * 16 + lr;
        bf16x8 ka0 = *(const bf16x8*)&Kl[r * 64 + ((lg ^ (lr & 7)) * 8)];
        bf16x8 ka1 = *(const bf16x8*)&Kl[r * 64 + (((4 + lg) ^ (lr & 7)) * 8)];
        cc = MFMA16(ka0, qf0, cc);
        cc = MFMA16(ka1, qf1, cc);
        c4[kg] = cc;
      }
      __builtin_amdgcn_s_setprio(0);
      float xs[16];                            // UNSCALED scores
      #pragma unroll
      for (int kg = 0; kg < 4; kg++)
        #pragma unroll
        for (int r = 0; r < 4; r++) xs[kg * 4 + r] = c4[kg][r];
      if (it == NT - 1) {                      // diagonal tile: causal mask
        int q = qw0 + lr;
        #pragma unroll
        for (int kg = 0; kg < 4; kg++)
          #pragma unroll
          for (int r = 0; r < 4; r++)
            if (j0 + kg * 16 + lg * 4 + r > q) xs[kg * 4 + r] = -1e30f;
      }
      float tm = fmaxf(xs[0], xs[1]);
      tm = fmaxf(fmaxf(tm, xs[2]), xs[3]);
      tm = fmaxf(fmaxf(tm, xs[4]), xs[5]);
      tm = fmaxf(fmaxf(tm, xs[6]), xs[7]);
      tm = fmaxf(fmaxf(tm, xs[8]), xs[9]);
      tm = fmaxf(fmaxf(tm, xs[10]), xs[11]);
      tm = fmaxf(fmaxf(tm, xs[12]), xs[13]);
      tm = fmaxf(fmaxf(tm, xs[14]), xs[15]);
      tm = fmaxf(tm, __shfl_xor(tm, 16));
      tm = fmaxf(tm, __shfl_xor(tm, 32));      // per-query max
      if (!__all(tm <= m + 64.f)) {            // defer-max: rescale only on growth
        float mn = fmaxf(m, tm);
        float al = exp2f((m - mn) * C8);
        m = mn;
        l *= al;
        float ar0 = __shfl(al, lg * 4 + 0), ar1 = __shfl(al, lg * 4 + 1);
        float ar2 = __shfl(al, lg * 4 + 2), ar3 = __shfl(al, lg * 4 + 3);
        o0[0] *= ar0; o0[1] *= ar1; o0[2] *= ar2; o0[3] *= ar3;
        o1[0] *= ar0; o1[1] *= ar1; o1[2] *= ar2; o1[3] *= ar3;
        o2[0] *= ar0; o2[1] *= ar1; o2[2] *= ar2; o2[3] *= ar3;
        o3[0] *= ar0; o3[1] *= ar1; o3[2] *= ar2; o3[3] *= ar3;
      }
      const float mnC = -m * C8;
      float p[16], rs = 0.f;
      #pragma unroll
      for (int r = 0; r < 16; r++) { p[r] = exp2f(fmaf(xs[r], C8, mnC)); rs += p[r]; }
      rs += __shfl_xor(rs, 16);
      rs += __shfl_xor(rs, 32);
      l += rs;
      // write P (query row = lr, keys kg*16+lg*4..+3) via cvt_pk (2 f32/inst)
      #pragma unroll
      for (int kg = 0; kg < 4; kg++) {
        int unit = (kg >> 1) * 64 + ((kg & 1) * 2 + (lg >> 1)) * 16 + lr;
        uint2 pk;
        pk.x = cvtpk(p[kg * 4 + 0], p[kg * 4 + 1]);
        pk.y = cvtpk(p[kg * 4 + 2], p[kg * 4 + 3]);
        *(uint2*)&Ps[w][unit * 8 + (lg & 1) * 4] = pk;
      }
      bf16x8 pa0 = *(const bf16x8*)&Ps[w][(lg * 16 + lr) * 8];
      bf16x8 pa1 = *(const bf16x8*)&Ps[w][(64 + lg * 16 + lr) * 8];
      __builtin_amdgcn_s_setprio(1);
      #pragma unroll
      for (int dg = 0; dg < 4; dg++) {
        int dr = dg * 16 + lr;
        bf16x8 v0 = *(const bf16x8*)&Vl[dr * 64 + ((lg ^ (lr & 7)) * 8)];
        bf16x8 v1 = *(const bf16x8*)&Vl[dr * 64 + (((4 + lg) ^ (lr & 7)) * 8)];
        f32x4& od = (dg == 0) ? o0 : (dg == 1) ? o1 : (dg == 2) ? o2 : o3;
        od = MFMA16(pa0, v0, od);
        od = MFMA16(pa1, v1, od);
      }
      __builtin_amdgcn_s_setprio(0);
      BARRIER();                               // reads of buf[cur] done
      cur ^= 1;
    }
    float li0 = 1.f / __shfl(l, lg * 4 + 0), li1 = 1.f / __shfl(l, lg * 4 + 1);
    float li2 = 1.f / __shfl(l, lg * 4 + 2), li3 = 1.f / __shfl(l, lg * 4 + 3);
    #pragma unroll
    for (int r = 0; r < 4; r++) {
      float lir = (r == 0) ? li0 : (r == 1) ? li1 : (r == 2) ? li2 : li3;
      size_t ro = (size_t)(qw0 + lg * 4 + r) * 1024;
      Op[ro + lr]      = f2b(o0[r] * lir);
      Op[ro + 16 + lr] = f2b(o1[r] * lir);
      Op[ro + 32 + lr] = f2b(o2[r] * lir);
      Op[ro + 48 + lr] = f2b(o3[r] * lir);
    }
  };
  run_tile(xp);                  // paired tiles: work = (x+1) + (32-x) = 33
  run_tile(31 - xp);
}

// ---------------- generic bf16 GEMM C = A(M,K) @ W(N,K)^T ----------------
// Coalesced gll16 staging, chunk-XOR swizzled LDS, double-buffered, counted-vmcnt.
// EPI: 0 = f32 (split-K via blockIdx.z); 3 = gate*acc+bias relu^2 -> bf16;
//      4 = gate*acc+bias + e4 -> f32; 8 = fused QKV (rotary q/k; V -> V^T direct);
//      9 = merged cq|h1 (f32 to Co / (float*)Cb).
template <int BM, int BN, int WR, int WC, int EPI>
__global__ __launch_bounds__(256) void gemm_bt(
    const u16* __restrict__ A, const u16* __restrict__ Bw,
    float* __restrict__ Co, u16* __restrict__ Cb, u16* __restrict__ Cb2, u16* __restrict__ Cb3,
    int gM, int N, int K, int KS,
    const float* __restrict__ e0, const float* __restrict__ e1,
    const float* __restrict__ e2, const float* __restrict__ e3,
    const float* __restrict__ e4) {
  constexpr int WM = BM / WR, WN = BN / WC;
  constexpr int FM = WM / 16, FN = WN / 16;
  constexpr int ACH = BM / 64, BCH = BN / 64;   // 16B units per thread per tile
  static_assert(WR * WC == 4 && BM % 64 == 0 && BN % 64 == 0, "cfg");
  __shared__ __align__(16) u16 As[2][BM * 32];
  __shared__ __align__(16) u16 Bs[2][BN * 32];
  const int tid = threadIdx.x;
  const int lane = tid & 63, wid = tid >> 6;
  const int wr = wid / WC, wc = wid % WC;
  const int bm = blockIdx.y * BM, bn = blockIdx.x * BN;
  const int lr = lane & 15, lg = lane >> 4;
  const int arow0 = bm + wr * WM, bcol0 = bn + wc * WN;
  const int kbeg = blockIdx.z * KS, kend = kbeg + KS;
  f32x4 acc[FM][FN] = {};
  auto stage = [&](int k0, int buf) {
    #pragma unroll
    for (int c = 0; c < ACH; c++) {
      int u = c * 256 + tid;
      int row = u >> 2, slot = u & 3;
      int cg = slot ^ (row & 3) ^ ((row >> 2) & 3);
      gll16(&A[(size_t)(bm + row) * K + k0 + cg * 8], &As[buf][u * 8]);
    }
    #pragma unroll
    for (int c = 0; c < BCH; c++) {
      int u = c * 256 + tid;
      int row = u >> 2, slot = u & 3;
      int cg = slot ^ (row & 3) ^ ((row >> 2) & 3);
      gll16(&Bw[(size_t)(bn + row) * K + k0 + cg * 8], &Bs[buf][u * 8]);
    }
  };
  stage(kbeg, 0);
  int cur = 0;
  for (int k0 = kbeg; k0 < kend; k0 += 32) {
    if (k0 + 32 < kend) {
      stage(k0 + 32, cur ^ 1);     // issue next tile FIRST, wait only for cur
      waitvm<ACH + BCH>();
    } else {
      waitvm<0>();
    }
    BARRIER();                      // cur staging visible to all waves
    const u16* Ab = As[cur];
    const u16* Bb = Bs[cur];
    bf16x8 af[FM], bfr[FN];
    #pragma unroll
    for (int i = 0; i < FM; i++) {
      int tr = wr * WM + i * 16 + lr;
      af[i] = *(const bf16x8*)&Ab[tr * 32 + ((lg ^ (tr & 3) ^ ((tr >> 2) & 3)) * 8)];
    }
    #pragma unroll
    for (int j = 0; j < FN; j++) {
      int tr = wc * WN + j * 16 + lr;
      bfr[j] = *(const bf16x8*)&Bb[tr * 32 + ((lg ^ (tr & 3) ^ ((tr >> 2) & 3)) * 8)];
    }
    #pragma unroll
    for (int i = 0; i < FM; i++)
      #pragma unroll
      for (int j = 0; j < FN; j++)
        acc[i][j] = __builtin_amdgcn_mfma_f32_16x16x32_bf16(af[i], bfr[j], acc[i][j], 0, 0, 0);
    BARRIER();                      // all reads of cur done before next overwrite
    cur ^= 1;
  }
  const int nb0 = bcol0 + lr;
  if constexpr (EPI == 0) {
    float* Cz = Co + (size_t)blockIdx.z * ((size_t)gM * N);
    #pragma unroll
    for (int i = 0; i < FM; i++)
      #pragma unroll
      for (int r = 0; r < 4; r++) {
        size_t mrow = (size_t)(arow0 + i * 16 + lg * 4 + r);
        #pragma unroll
        for (int j = 0; j < FN; j++)
          Cz[mrow * N + nb0 + j * 16] = acc[i][j][r];
      }
  } else if constexpr (EPI == 9) {
    // merged cq|h1: bn==0 -> cq (f32, stride 64); else h1 (f32, stride 256)
    if (bn == 0) {
      #pragma unroll
      for (int i = 0; i < FM; i++)
        #pragma unroll
        for (int r = 0; r < 4; r++) {
          size_t mrow = (size_t)(arow0 + i * 16 + lg * 4 + r);
          #pragma unroll
          for (int j = 0; j < FN; j++)
            Co[mrow * 64 + nb0 + j * 16] = acc[i][j][r];
        }
    } else {
      float* H = (float*)Cb;
      const int c0 = bcol0 - 64 + lr;
      #pragma unroll
      for (int i = 0; i < FM; i++)
        #pragma unroll
        for (int r = 0; r < 4; r++) {
          size_t mrow = (size_t)(arow0 + i * 16 + lg * 4 + r);
          #pragma unroll
          for (int j = 0; j < FN; j++)
            H[mrow * 256 + c0 + j * 16] = acc[i][j][r];
        }
    }
  } else if constexpr (EPI == 8) {
    // fused QKV; requires WN==64 (wave covers one head). V goes to V^T directly.
    if (bn < 2048) {
      u16* dst = (bn < 1024) ? Cb : Cb2;
      const int nq0 = (bcol0 & 1023) + lr;
      #pragma unroll
      for (int i = 0; i < FM; i++)
        #pragma unroll
        for (int r = 0; r < 4; r++) {
          size_t mrow = (size_t)(arow0 + i * 16 + lg * 4 + r);
          int t = (int)(mrow & 2047);
          #pragma unroll
          for (int j = 0; j < 2; j++) {
            int d = lr + j * 16;
            float cth = e0[t * 32 + d], sth = e1[t * 32 + d];
            float x1 = acc[i][j][r], x2 = acc[i][j + 2][r];
            dst[mrow * 1024 + nq0 + j * 16]       = f2b(x1 * cth + x2 * sth);
            dst[mrow * 1024 + nq0 + (j + 2) * 16] = f2b(x2 * cth - x1 * sth);
          }
        }
    } else {
      // V^T[(b*16+h)*64 + d][t]; per (i,j) the 4 r-values are 4 consecutive t
      const int hh = (bcol0 - 2048) >> 6;
      const int bb = arow0 >> 11;
      const int t0 = (arow0 & 2047) + lg * 4;
      u16* vt = Cb3 + ((size_t)(bb * 16 + hh) * 64) * 2048;
      #pragma unroll
      for (int i = 0; i < FM; i++)
        #pragma unroll
        for (int j = 0; j < FN; j++) {
          u16x4 pk;
          pk.x = f2b(acc[i][j][0]); pk.y = f2b(acc[i][j][1]);
          pk.z = f2b(acc[i][j][2]); pk.w = f2b(acc[i][j][3]);
          *(u16x4*)&vt[(size_t)(lr + j * 16) * 2048 + t0 + i * 16] = pk;
        }
    }
  } else {
    // EPI 3/4: gate_out = 1+tanh(ogs*d) = 2/(1+exp2(ogs*d*NEG2LOG2E))
    const float cg = e3[0] * NEG2LOG2E;
    float gB[FN][8], bias[FN];
    #pragma unroll
    for (int j = 0; j < FN; j++) {
      int n = nb0 + j * 16;
      bias[j] = e2[n];
      #pragma unroll
      for (int rr = 0; rr < 8; rr++) gB[j][rr] = e1[(size_t)rr * N + n];
    }
    #pragma unroll
    for (int i = 0; i < FM; i++)
      #pragma unroll
      for (int r = 0; r < 4; r++) {
        size_t mrow = (size_t)(arow0 + i * 16 + lg * 4 + r);
        float go8[8];
        #pragma unroll
        for (int rr = 0; rr < 8; rr++) go8[rr] = e0[mrow * 8 + rr];
        #pragma unroll
        for (int j = 0; j < FN; j++) {
          float d = 0.f;
          #pragma unroll
          for (int rr = 0; rr < 8; rr++) d += go8[rr] * gB[j][rr];
          float gate = 2.f * __builtin_amdgcn_rcpf(1.f + exp2f(cg * d));
          float v = acc[i][j][r] * gate + bias[j];
          if constexpr (EPI == 3) {
            v = fmaxf(v, 0.f); v *= v;
            Cb[mrow * N + nb0 + j * 16] = f2b(v);
          } else {
            v += e4[mrow * N + nb0 + j * 16];
            Co[mrow * N + nb0 + j * 16] = v;
          }
        }
      }
  }
}

// -------- fused ctx + gate1(+LN1 -> A1 direct) + gate2 (-> gb2, go2) --------
__global__ __launch_bounds__(256) void k_ctxgate(
    const float* __restrict__ cq, const float* __restrict__ pr,
    const float* __restrict__ h1, const float* __restrict__ lg1,
    const float* __restrict__ lb1,
    const float* __restrict__ f_m1w, const float* __restrict__ f_m1b,
    const float* __restrict__ f_m2w, const float* __restrict__ f_m2b,
    const float* __restrict__ f_ogw, const float* __restrict__ f_ogb,
    const float* __restrict__ p_m1w, const float* __restrict__ p_m1b,
    const float* __restrict__ p_m2w, const float* __restrict__ p_m2b,
    const float* __restrict__ p_ogw, const float* __restrict__ p_ogb,
    u16* __restrict__ a1, float* __restrict__ go1,
    float* __restrict__ gb2, float* __restrict__ go2) {
  __shared__ float pl[64 * 65];               // protos; reused as hs[16][256]
  __shared__ __align__(16) float cqs[16][64];
  __shared__ float wl[16][64];
  __shared__ __align__(16) float cs[16][64];
  __shared__ __align__(16) float gls[16][128];
  __shared__ float sLN[16][2];
  const int tid = threadIdx.x;
  const int row0 = blockIdx.x * 16;
  for (int idx = tid; idx < 4096; idx += 256) pl[(idx >> 6) * 65 + (idx & 63)] = pr[idx];
  for (int idx = tid; idx < 1024; idx += 256)
    cqs[idx >> 6][idx & 63] = cq[(size_t)row0 * 64 + idx];
  __syncthreads();
  // scores + softmax(64): thread = (row, pg); protos p = pg*4..+3
  const int row = tid >> 4, pg = tid & 15;
  float sc[4];
  #pragma unroll
  for (int q = 0; q < 4; q++) {
    int p = pg * 4 + q;
    float s = 0.f;
    #pragma unroll
    for (int k4 = 0; k4 < 16; k4++) {
      float4 cv = *(const float4*)&cqs[row][k4 * 4];
      const float* pw = &pl[p * 65 + k4 * 4];
      s += cv.x * pw[0] + cv.y * pw[1] + cv.z * pw[2] + cv.w * pw[3];
    }
    sc[q] = s * 0.125f;
  }
  float mx = fmaxf(fmaxf(sc[0], sc[1]), fmaxf(sc[2], sc[3]));
  #pragma unroll
  for (int off = 1; off <= 8; off <<= 1) mx = fmaxf(mx, __shfl_xor(mx, off));
  float e[4], sum = 0.f;
  #pragma unroll
  for (int q = 0; q < 4; q++) { e[q] = __expf(sc[q] - mx); sum += e[q]; }
  #pragma unroll
  for (int off = 1; off <= 8; off <<= 1) sum += __shfl_xor(sum, off);
  float inv = 1.f / sum;
  #pragma unroll
  for (int q = 0; q < 4; q++) wl[row][pg * 4 + q] = e[q] * inv;
  __syncthreads();
  #pragma unroll
  for (int q = 0; q < 4; q++) {
    int c = pg * 4 + q;
    float a = 0.f;
    for (int p = 0; p < 64; p++) a += wl[row][p] * pl[p * 65 + c];
    cs[row][c] = a;
  }
  __syncthreads();                 // cs done; pl (protos) now dead
  // ---- load h1 tile into pl region; per-row LN stats ----
  float* hs = pl;
  for (int idx = tid; idx < 4096; idx += 256)
    hs[idx] = h1[(size_t)row0 * 256 + idx];
  __syncthreads();
  {
    int r = tid >> 4, sub = tid & 15;
    float s = 0.f, s2 = 0.f;
    #pragma unroll
    for (int k = 0; k < 16; k++) {
      float v = hs[r * 256 + sub * 16 + k];
      s += v; s2 += v * v;
    }
    #pragma unroll
    for (int mk = 1; mk <= 8; mk <<= 1) { s += __shfl_xor(s, mk); s2 += __shfl_xor(s2, mk); }
    if (sub == 0) {
      float mu = s * (1.f / 256.f);
      sLN[r][0] = mu;
      sLN[r][1] = rsqrtf(fmaxf(s2 * (1.f / 256.f) - mu * mu, 0.f) + 1e-5f);
    }
  }
  __syncthreads();
  // ---- gate 1: m1+gelu -> gls; og -> go1; m2 -> sigmoid; A1 = LN(h1)*gb ----
  for (int idx = tid; idx < 2048; idx += 256) {
    int r = idx >> 7, mh = idx & 127;
    const float* wrow = &f_m1w[(size_t)mh * 64];
    float a = f_m1b[mh];
    #pragma unroll
    for (int k4 = 0; k4 < 16; k4++) {
      float4 w4 = *(const float4*)&wrow[k4 * 4];
      float4 c4v = *(const float4*)&cs[r][k4 * 4];
      a += c4v.x * w4.x + c4v.y * w4.y + c4v.z * w4.z + c4v.w * w4.w;
    }
    gls[r][mh] = 0.5f * a * (1.f + erff(a * 0.70710678f));
  }
  if (tid < 128) {
    int r = tid >> 3, rr = tid & 7;
    const float* wrow = &f_ogw[(size_t)rr * 64];
    float a = f_ogb[rr];
    #pragma unroll
    for (int k4 = 0; k4 < 16; k4++) {
      float4 w4 = *(const float4*)&wrow[k4 * 4];
      float4 c4v = *(const float4*)&cs[r][k4 * 4];
      a += c4v.x * w4.x + c4v.y * w4.y + c4v.z * w4.z + c4v.w * w4.w;
    }
    go1[(size_t)(row0 + r) * 8 + rr] = a;
  }
  __syncthreads();
  {
    int n = tid;
    float acc2[16];
    #pragma unroll
    for (int r = 0; r < 16; r++) acc2[r] = f_m2b[n];
    for (int k4 = 0; k4 < 32; k4++) {
      float4 wv = *(const float4*)&f_m2w[(size_t)n * 128 + k4 * 4];
      #pragma unroll
      for (int r = 0; r < 16; r++) {
        float4 g = *(const float4*)&gls[r][k4 * 4];
        acc2[r] += g.x * wv.x + g.y * wv.y + g.z * wv.z + g.w * wv.w;
      }
    }
    float gvn = lg1[n], bvn = lb1[n];
    #pragma unroll
    for (int r = 0; r < 16; r++) {
      float sig = 1.f / (1.f + __expf(-acc2[r]));
      float y = (hs[r * 256 + n] - sLN[r][0]) * sLN[r][1] * gvn + bvn;
      a1[(size_t)(row0 + r) * 256 + n] = f2b(y * sig);
    }
  }
  __syncthreads();
  // ---- gate 2 -> gb2, go2 ----
  for (int idx = tid; idx < 2048; idx += 256) {
    int r = idx >> 7, mh = idx & 127;
    const float* wrow = &p_m1w[(size_t)mh * 64];
    float a = p_m1b[mh];
    #pragma unroll
    for (int k4 = 0; k4 < 16; k4++) {
      float4 w4 = *(const float4*)&wrow[k4 * 4];
      float4 c4v = *(const float4*)&cs[r][k4 * 4];
      a += c4v.x * w4.x + c4v.y * w4.y + c4v.z * w4.z + c4v.w * w4.w;
    }
    gls[r][mh] = 0.5f * a * (1.f + erff(a * 0.70710678f));
  }
  if (tid < 128) {
    int r = tid >> 3, rr = tid & 7;
    const float* wrow = &p_ogw[(size_t)rr * 64];
    float a = p_ogb[rr];
    #pragma unroll
    for (int k4 = 0; k4 < 16; k4++) {
      float4 w4 = *(const float4*)&wrow[k4 * 4];
      float4 c4v = *(const float4*)&cs[r][k4 * 4];
      a += c4v.x * w4.x + c4v.y * w4.y + c4v.z * w4.z + c4v.w * w4.w;
    }
    go2[(size_t)(row0 + r) * 8 + rr] = a;
  }
  __syncthreads();
  {
    int n = tid;
    float acc2[16];
    #pragma unroll
    for (int r = 0; r < 16; r++) acc2[r] = p_m2b[n];
    for (int k4 = 0; k4 < 32; k4++) {
      float4 wv = *(const float4*)&p_m2w[(size_t)n * 128 + k4 * 4];
      #pragma unroll
      for (int r = 0; r < 16; r++) {
        float4 g = *(const float4*)&gls[r][k4 * 4];
        acc2[r] += g.x * wv.x + g.y * wv.y + g.z * wv.z + g.w * wv.w;
      }
    }
    #pragma unroll
    for (int r = 0; r < 16; r++)
      gb2[(size_t)(row0 + r) * 256 + n] = 1.f / (1.f + __expf(-acc2[r]));
  }
}

// ---------------- LN(row 256) over summed splits * gate_basis -> bf16 ----------------
template <int NS>
__global__ __launch_bounds__(256) void k_lnmul(const float* __restrict__ h,
                                               const float* __restrict__ g,
                                               const float* __restrict__ b,
                                               const float* __restrict__ gbm,
                                               u16* __restrict__ o) {
  __shared__ float sb[4];
  int row = blockIdx.x, n = threadIdx.x;
  float x = 0.f;
  #pragma unroll
  for (int z = 0; z < NS; z++) x += h[(size_t)z * Mc * 256 + (size_t)row * 256 + n];
  float mu = bsum256(x, sb) * (1.f / 256.f);
  float d = x - mu;
  float var = bsum256(d * d, sb) * (1.f / 256.f);
  float y = d * rsqrtf(var + 1e-5f) * g[n] + b[n];
  o[(size_t)row * 256 + n] = f2b(y * gbm[(size_t)row * 256 + n]);
}

// ---------------- host launch ----------------
extern "C" void kernel_launch(void* const* d_in, const int* in_sizes, int n_in,
                              void* d_out, int out_size, void* d_ws, size_t ws_size,
                              hipStream_t stream) {
  (void)in_sizes; (void)n_in; (void)out_size; (void)ws_size;
  const float* x      = (const float*)d_in[0];
  const float* cosb   = (const float*)d_in[1];
  const float* sinb   = (const float*)d_in[2];
  const float* wq     = (const float*)d_in[3];
  const float* wk     = (const float*)d_in[4];
  const float* wv     = (const float*)d_in[5];
  const float* wo     = (const float*)d_in[6];
  const float* cb_qw  = (const float*)d_in[7];
  const float* protos = (const float*)d_in[8];
  const float* fc_bw  = (const float*)d_in[9];
  const float* fc_lg  = (const float*)d_in[10];
  const float* fc_lb  = (const float*)d_in[11];
  const float* fc_tm  = (const float*)d_in[12];
  const float* fc_b   = (const float*)d_in[13];
  const float* fc_m1w = (const float*)d_in[14];
  const float* fc_m1b = (const float*)d_in[15];
  const float* fc_m2w = (const float*)d_in[16];
  const float* fc_m2b = (const float*)d_in[17];
  const float* fc_ogw = (const float*)d_in[18];
  const float* fc_ogb = (const float*)d_in[19];
  const float* fc_ogB = (const float*)d_in[20];
  const float* fc_ogs = (const float*)d_in[21];
  const float* pj_bw  = (const float*)d_in[22];
  const float* pj_lg  = (const float*)d_in[23];
  const float* pj_lb  = (const float*)d_in[24];
  const float* pj_tm  = (const float*)d_in[25];
  const float* pj_b   = (const float*)d_in[26];
  const float* pj_m1w = (const float*)d_in[27];
  const float* pj_m1b = (const float*)d_in[28];
  const float* pj_m2w = (const float*)d_in[29];
  const float* pj_m2b = (const float*)d_in[30];
  const float* pj_ogw = (const float*)d_in[31];
  const float* pj_ogb = (const float*)d_in[32];
  const float* pj_ogB = (const float*)d_in[33];
  const float* pj_ogs = (const float*)d_in[34];
  char* ws = (char*)d_ws;
  float* outp = (float*)d_out;
  auto U = [&](size_t o) { return (u16*)(ws + o); };
  auto F = [&](size_t o) { return (float*)(ws + o); };
  const float* nf = nullptr;
  u16* nu = nullptr;

  // 0) merged weight conversions
  {
    Cvt9 a;
    const float* srcs[9] = {wq, wk, wv, wo, cb_qw, fc_bw, fc_tm, pj_bw, pj_tm};
    size_t offs[9] = {O_WQ, O_WK, O_WV, O_WO, O_CBQ, O_FCBW, O_FCTM, O_PJBW, O_PJTM};
    int ns[9] = {Ec*Ec, Ec*Ec, Ec*Ec, Ec*Ec, Cc*Ec, BFc*Ec, F4c*BFc, BFc*F4c, Ec*BFc};
    int cum = 0;
    for (int s = 0; s < 9; s++) {
      a.s[s] = srcs[s]; a.d[s] = U(offs[s]); a.cum[s] = cum; cum += ns[s] / 4;
    }
    a.cum[9] = cum;
    k_cvt<<<dim3(cum / 256), dim3(256), 0, stream>>>(a);
  }
  // 1) xn = rms(x)
  k_rms<<<dim3(Mc), dim3(256), 0, stream>>>(x, U(O_XN));
  // 2) fused QKV projection: rotary q/k -> QB/KB; v -> V^T direct
  gemm_bt<128,128,2,2,8><<<dim3(24,32), dim3(256), 0, stream>>>(U(O_XN), U(O_WQ), nullptr, U(O_QB), U(O_KB), U(O_VT), Mc, 3072, Ec, Ec, cosb, sinb, nf, nf, nf);
  // 3) attention -> bf16 (reuses XN region); paired q-tiles, 512 blocks (r7)
  k_attn<<<dim3(512), dim3(256), 0, stream>>>(U(O_QB), U(O_KB), U(O_VT), U(O_XN));
  // 4) wo projection split-K x2 -> partials
  gemm_bt<128,128,2,2,0><<<dim3(8,32,2), dim3(256), 0, stream>>>(U(O_XN), U(O_WO), F(O_WOP), nu, nu, nu, Mc, Ec, Ec, 512, nf, nf, nf, nf, nf);
  // 5) x2 = p0+p1+x (f32 out) ; xn2 = rms(x2)
  k_rms2c<<<dim3(Mc), dim3(256), 0, stream>>>(F(O_WOP), x, F(O_X2), U(O_XN));
  // 6) merged cq|h1 GEMM: B = [cb_qw ; fc_bw] (contiguous, N=320)
  gemm_bt<64,64,1,4,9><<<dim3(5,64), dim3(256), 0, stream>>>(U(O_XN), U(O_CBQ), F(O_CQ), (u16*)F(O_H1), nu, nu, Mc, 320, Ec, Ec, nf, nf, nf, nf, nf);
  // 7) fused ctx + gate1(+LN1 -> A1) + gate2 (-> gb2, go2)
  k_ctxgate<<<dim3(Mc / 16), dim3(256), 0, stream>>>(F(O_CQ), protos,
      F(O_H1), fc_lg, fc_lb,
      fc_m1w, fc_m1b, fc_m2w, fc_m2b, fc_ogw, fc_ogb,
      pj_m1w, pj_m1b, pj_m2w, pj_m2b, pj_ogw, pj_ogb,
      U(O_A1), F(O_GO1), F(O_GB2), F(O_GO2));
  // 8) h = relu^2(gated fc_tm GEMM)
  gemm_bt<128,128,2,2,3><<<dim3(32,32), dim3(256), 0, stream>>>(U(O_A1), U(O_FCTM), nullptr, U(O_HBF), nu, nu, Mc, F4c, BFc, BFc, F(O_GO1), fc_ogB, fc_b, fc_ogs, nf);
  // 9) pj: h2 = h @ pj_bw.T (64x64, split-K x4); A2 = LN(h2)*gb2
  gemm_bt<64,64,1,4,0><<<dim3(4,64,4), dim3(256), 0, stream>>>(U(O_HBF), U(O_PJBW), F(O_H2), nu, nu, nu, Mc, BFc, F4c, 1024, nf, nf, nf, nf, nf);
  k_lnmul<4><<<dim3(Mc), dim3(256), 0, stream>>>(F(O_H2), pj_lg, pj_lb, F(O_GB2), U(O_A2));
  // 10) out = gated pj_tm GEMM + x2  (64x64 tiles, 4 blocks/CU at K=256)
  gemm_bt<64,64,1,4,4><<<dim3(16,64), dim3(256), 0, stream>>>(U(O_A2), U(O_PJTM), outp, nu, nu, nu, Mc, Ec, BFc, BFc, F(O_GO2), pj_ogB, pj_b, pj_ogs, F(O_X2));
}